// Round 5
// baseline (1784.164 us; speedup 1.0000x reference)
//
#include <hip/hip_runtime.h>
#include <math.h>

// Problem constants
#define CC 62
#define TT 2000
#define BB 256
#define VECN 1953          // C*(C+1)/2
#define HID 64
#define NCLS 3
#define NPART 4            // t-parts for Grammian partials
#define TCHUNK 500         // TT / NPART
#define TTILE 100          // t-tile
#define NTILES 5           // TCHUNK / TTILE
#define LDXF 68            // sXf row stride (floats)
#define NG 31              // disjoint pairs per round

__device__ __forceinline__ void decodePi(int pi, int& i, int& j)
{
    int ii = 0, rem = pi;
    while (rem >= CC - ii) { rem -= (CC - ii); ++ii; }
    i = ii; j = ii + rem;
}

// round-robin (circle method) pair schedule: 31 disjoint pairs, 61 rounds
__device__ __forceinline__ void pairPQ(int r, int k, int& p, int& q)
{
    if (k == 0) { p = 0; q = 1 + (r + 60) % 61; }
    else {
        p = 1 + (r + k - 1) % 61;
        q = 1 + (r + 60 - k) % 61;
    }
    if (p > q) { int t = p; p = q; q = t; }
}

// ---------------------------------------------------------------------------
// K1: raw-x partial Grammian S = sum_t x x^T (packed triu) and partial sums
//     m = sum_t x over a 500-sample t-chunk. fp32 staging + fp32 products,
//     upgraded to fp64 accumulators once per 100-t tile (error ~1e-7 on cov).
//     Conv is algebraically removed: cov(Wx+b) = W cov(x) W^T (done in k2).
// grid = (B, NPART), block = 192 (3 waves; 136 gram threads, 4x4 reg tiles,
// float4 LDS reads: 2 reads per 16 FMA).
// ---------------------------------------------------------------------------
__global__ __launch_bounds__(192) void k1_gram(
    const float* __restrict__ x, double* __restrict__ S,
    double* __restrict__ M)
{
    const int b = blockIdx.x, part = blockIdx.y, tid = threadIdx.x;

    __shared__ float sXf[TTILE * LDXF];   // [t][c], 27.2KB

    // Grammian mapping: thread u<136 -> group-pair (gi<=gj) of 16 groups of 4
    int gi = 0, gj = 0;
    if (tid < 136) {
        int g = 0, rem = tid;
        while (rem >= 16 - g) { rem -= (16 - g); ++g; }
        gi = g; gj = g + rem;
    }
    const bool gram = (tid < 136);
    const int c0 = 4 * gi, c1 = 4 * gj;

    double acc64[4][4];
#pragma unroll
    for (int a = 0; a < 4; ++a)
#pragma unroll
        for (int c = 0; c < 4; ++c) acc64[a][c] = 0.0;
    double macc = 0.0;

    // zero-pad channels 62..67 once (loaders never touch them)
    for (int t = tid; t < TTILE; t += 192) {
#pragma unroll
        for (int c = CC; c < LDXF; ++c) sXf[t * LDXF + c] = 0.0f;
    }

    const float* xb = x + (size_t)b * CC * TT;
    const int tbase = part * TCHUNK;

    for (int tile = 0; tile < NTILES; ++tile) {
        const int t0 = tbase + tile * TTILE;
        __syncthreads();   // previous tile fully consumed (covers pad init too)
        // coalesced float4 loads along t; transpose into [t][c] via b32 writes
        for (int e = tid; e < CC * (TTILE / 4); e += 192) {
            int row = e / (TTILE / 4), seg = e - row * (TTILE / 4);
            float4 v = *reinterpret_cast<const float4*>(
                xb + (size_t)row * TT + t0 + seg * 4);
            int tt = seg * 4;
            sXf[(tt + 0) * LDXF + row] = v.x;
            sXf[(tt + 1) * LDXF + row] = v.y;
            sXf[(tt + 2) * LDXF + row] = v.z;
            sXf[(tt + 3) * LDXF + row] = v.w;
        }
        __syncthreads();
        // per-channel sums (fp32 within tile, fp64 upgrade)
        if (tid < CC) {
            float ms = 0.0f;
            for (int t = 0; t < TTILE; ++t) ms += sXf[t * LDXF + tid];
            macc += (double)ms;
        }
        if (gram) {
            float a32[4][4];
#pragma unroll
            for (int a = 0; a < 4; ++a)
#pragma unroll
                for (int c = 0; c < 4; ++c) a32[a][c] = 0.0f;
            for (int t = 0; t < TTILE; ++t) {
                const float* rowt = &sXf[t * LDXF];
                float4 A = *reinterpret_cast<const float4*>(&rowt[c0]);
                float4 Bv = *reinterpret_cast<const float4*>(&rowt[c1]);
                a32[0][0] += A.x * Bv.x; a32[0][1] += A.x * Bv.y;
                a32[0][2] += A.x * Bv.z; a32[0][3] += A.x * Bv.w;
                a32[1][0] += A.y * Bv.x; a32[1][1] += A.y * Bv.y;
                a32[1][2] += A.y * Bv.z; a32[1][3] += A.y * Bv.w;
                a32[2][0] += A.z * Bv.x; a32[2][1] += A.z * Bv.y;
                a32[2][2] += A.z * Bv.z; a32[2][3] += A.z * Bv.w;
                a32[3][0] += A.w * Bv.x; a32[3][1] += A.w * Bv.y;
                a32[3][2] += A.w * Bv.z; a32[3][3] += A.w * Bv.w;
            }
#pragma unroll
            for (int a = 0; a < 4; ++a)
#pragma unroll
                for (int c = 0; c < 4; ++c) acc64[a][c] += (double)a32[a][c];
        }
    }

    if (tid < CC) M[((size_t)b * NPART + part) * 64 + tid] = macc;

    if (gram) {
        double* Sb = S + ((size_t)b * NPART + part) * VECN;
#pragma unroll
        for (int a = 0; a < 4; ++a) {
            int i = c0 + a;
#pragma unroll
            for (int c = 0; c < 4; ++c) {
                int j = c1 + c;
                if (j < CC && i <= j) {
                    int pi = i * CC - (i * (i - 1)) / 2 + (j - i);
                    Sb[pi] = acc64[a][c];
                }
            }
        }
    }
}

// ---------------------------------------------------------------------------
// K2: wave-per-matrix. Assemble A = W cov_x W^T + eps I into LDS (XOR-swizzled
//     columns), one-sided Jacobi with 2 lanes per pair (1 DPP shfl reduction,
//     single-wave block -> near-free barriers), then
//     log_cov = G diag(log lam / lam^2) G^T -> fp32 triu vec.
// grid = B, block = 64. LDS ~56KB.
// ---------------------------------------------------------------------------
// G column-major, 64 rows/col; 2-row chunk k of col c stored at chunk k^(c&31)
// (keeps 16B-aligned double2 access, spreads banks across columns).
__device__ __forceinline__ double2* gchunk(double* sG, int c, int k)
{
    return reinterpret_cast<double2*>(sG + c * 64 + (((k) ^ (c & 31)) << 1));
}
__device__ __forceinline__ double* gelem(double* sG, int c, int r)
{
    return sG + c * 64 + ((((r >> 1) ^ (c & 31)) << 1) | (r & 1));
}

__global__ __launch_bounds__(64) void k2_eig(
    const double* __restrict__ S, const double* __restrict__ M,
    const float* __restrict__ cw, float* __restrict__ vecout)
{
    const int b = blockIdx.x, tid = threadIdx.x;

    __shared__ double sG[CC * 64];     // 31.7KB, swizzled columns
    __shared__ double sC[VECN];        // 15.6KB packed cov_x
    __shared__ int    sPair[61 * NG];  // 7.6KB
    __shared__ double sNorm[64];
    __shared__ double sD[64];
    __shared__ double sMean[64];

    // pair schedule
    for (int e = tid; e < 61 * NG; e += 64) {
        int r = e / NG, k = e - r * NG;
        int p, q; pairPQ(r, k, p, q);
        sPair[e] = p | (q << 8);
    }
    // zero G (incl pad rows)
    for (int e = tid; e < CC * 64; e += 64) sG[e] = 0.0;
    if (tid < CC) {
        double mm = 0.0;
        for (int p = 0; p < NPART; ++p) mm += M[((size_t)b * NPART + p) * 64 + tid];
        sMean[tid] = mm / (double)TT;
    }
    __syncthreads();

    // packed cov_x = (S - T m m^T)/(T-1)
    for (int pi = tid; pi < VECN; pi += 64) {
        int i, j; decodePi(pi, i, j);
        double s = 0.0;
        for (int p = 0; p < NPART; ++p) s += S[((size_t)b * NPART + p) * VECN + pi];
        sC[pi] = (s - (double)TT * sMean[i] * sMean[j]) / 1999.0;
    }
    __syncthreads();

    // A = W C W^T + eps I. Lane j: U = C w_j (fp64, 62 regs, independent
    // accumulators), then A[i][j] = w_i . U via scalar w loads.
    if (tid < CC) {
        const int j = tid;
        float wj[CC];
#pragma unroll
        for (int l = 0; l < CC; ++l) wj[l] = cw[j * CC + l];
        double U[CC];
#pragma unroll
        for (int k = 0; k < CC; ++k) U[k] = 0.0;
        for (int l = 0; l < CC; ++l) {
            double cl = (double)wj[l];
            int idx = l;
            // k < l: element (k,l), stride 61-k ; k >= l: element (l,k), stride 1
            for (int k = 0; k < l; ++k) { U[k] += sC[idx] * cl; idx += 61 - k; }
            for (int k = l; k < CC; ++k) { U[k] += sC[idx] * cl; idx += 1; }
        }
        for (int i = 0; i < CC; ++i) {
            const float* wi = cw + i * CC;
            double a0 = 0.0, a1 = 0.0, a2 = 0.0, a3 = 0.0;
#pragma unroll
            for (int k = 0; k < 60; k += 4) {
                a0 += (double)wi[k] * U[k];
                a1 += (double)wi[k + 1] * U[k + 1];
                a2 += (double)wi[k + 2] * U[k + 2];
                a3 += (double)wi[k + 3] * U[k + 3];
            }
            a0 += (double)wi[60] * U[60];
            a1 += (double)wi[61] * U[61];
            double a = (a0 + a1) + (a2 + a3);
            if (i == j) a += 1e-3;
            *gelem(sG, j, i) = a;
        }
        // initial column norm
        double n = 0.0;
        for (int i = 0; i < CC; ++i) { double v = *gelem(sG, j, i); n += v * v; }
        sNorm[j] = n;
    }
    __syncthreads();

    // one-sided Jacobi: lanes (2g, 2g+1) handle pair g; half h owns rows
    // 32h..32h+31 (16 double2 chunks). Reduction = single DPP shfl.
    const int g = tid >> 1, h = tid & 1;
    const bool act = (g < NG);
    const int gc = act ? g : 0;
    const int kbase = h * 16;

    for (int sweep = 0; sweep < 18; ++sweep) {
        int rotAny = 0;
        for (int r = 0; r < 61; ++r) {
            int pq = sPair[r * NG + gc];
            int p = pq & 255, q = pq >> 8;
            double np = sNorm[p], nq = sNorm[q];
            double2 cp[16], cq[16];
#pragma unroll
            for (int k = 0; k < 16; ++k) cp[k] = *gchunk(sG, p, kbase + k);
#pragma unroll
            for (int k = 0; k < 16; ++k) cq[k] = *gchunk(sG, q, kbase + k);
            double d = 0.0;
#pragma unroll
            for (int k = 0; k < 16; ++k)
                d += cp[k].x * cq[k].x + cp[k].y * cq[k].y;
            d += __shfl_xor(d, 1, 64);
            if (act && d * d > np * nq * 1e-12) {
                rotAny = 1;
                float thf = (float)(nq - np) / (2.0f * (float)d);
                float af = fabsf(thf);
                float tf = 1.0f / (af + sqrtf(af * af + 1.0f));
                if (thf < 0.0f) tf = -tf;
                float cf = rsqrtf(tf * tf + 1.0f);
                double c = (double)cf, sn = (double)(tf * cf);
#pragma unroll
                for (int k = 0; k < 16; ++k) {
                    double2 a = cp[k], bv = cq[k];
                    *gchunk(sG, p, kbase + k) =
                        make_double2(c * a.x - sn * bv.x, c * a.y - sn * bv.y);
                    *gchunk(sG, q, kbase + k) =
                        make_double2(sn * a.x + c * bv.x, sn * a.y + c * bv.y);
                }
                double td = (double)tf * d;
                if (h == 0) sNorm[p] = np - td;
                else        sNorm[q] = nq + td;
            }
            __syncthreads();
        }
        if (__ballot(rotAny != 0) == 0ull) break;
    }

    // lam_k^2 = ||g_k||^2 ; sD_k = log(max(lam,1e-6))/lam^2
    if (tid < CC) {
        double n = 0.0;
        for (int i = 0; i < CC; ++i) { double v = *gelem(sG, tid, i); n += v * v; }
        double lamv = sqrt(n);
        sD[tid] = log(fmax(lamv, 1e-6)) / n;
    }
    __syncthreads();

    // log_cov[i][j] = sum_k sD_k G[i][k] G[j][k]
    float* vb = vecout + (size_t)b * VECN;
    for (int pi = tid; pi < VECN; pi += 64) {
        int i, j; decodePi(pi, i, j);
        double a = 0.0;
#pragma unroll 2
        for (int k = 0; k < CC; ++k)
            a += sD[k] * (*gelem(sG, k, i)) * (*gelem(sG, k, j));
        vb[pi] = (float)a;
    }
}

// ---------------------------------------------------------------------------
// K3: feat = relu(vec @ proj_w^T + proj_b); logits = feat @ head_w^T + head_b
// grid = B, block = 256 (4-way K-split per hidden unit)
// ---------------------------------------------------------------------------
__global__ __launch_bounds__(256) void k3_mlp(
    const float* __restrict__ vecin, const float* __restrict__ pw,
    const float* __restrict__ pb, const float* __restrict__ hw,
    const float* __restrict__ hb, float* __restrict__ out)
{
    const int b = blockIdx.x;
    const int tid = threadIdx.x;
    __shared__ float sv[VECN];
    __shared__ float sp[4][HID];
    __shared__ float sf[HID];
    for (int k = tid; k < VECN; k += 256) sv[k] = vecin[(size_t)b * VECN + k];
    __syncthreads();
    const int h = tid & 63, pp = tid >> 6;
    const int k0 = (pp * VECN) >> 2, k1 = ((pp + 1) * VECN) >> 2;
    float acc = 0.0f;
    const float* w = pw + (size_t)h * VECN;
    for (int k = k0; k < k1; ++k) acc += sv[k] * w[k];
    sp[pp][h] = acc;
    __syncthreads();
    if (tid < HID) {
        float a = sp[0][tid] + sp[1][tid] + sp[2][tid] + sp[3][tid] + pb[tid];
        sf[tid] = fmaxf(a, 0.0f);
    }
    __syncthreads();
    if (tid < NCLS) {
        float o = hb[tid];
        for (int hh = 0; hh < HID; ++hh) o += sf[hh] * hw[tid * HID + hh];
        out[b * NCLS + tid] = o;
    }
}

// ---------------------------------------------------------------------------
extern "C" void kernel_launch(void* const* d_in, const int* in_sizes, int n_in,
                              void* d_out, int out_size, void* d_ws, size_t ws_size,
                              hipStream_t stream)
{
    const float* x  = (const float*)d_in[0];
    const float* cw = (const float*)d_in[1];
    // d_in[2] = conv bias: cancels in covariance, unused
    const float* pw = (const float*)d_in[3];
    const float* pb = (const float*)d_in[4];
    const float* hw = (const float*)d_in[5];
    const float* hb = (const float*)d_in[6];
    float* out = (float*)d_out;

    // workspace: S [B*NPART][VECN] fp64 (16MB), M [B*NPART][64] fp64 (0.5MB),
    //            vec [B][VECN] fp32 (2MB)
    double* S = (double*)d_ws;
    double* M = S + (size_t)BB * NPART * VECN;
    float* vec = (float*)(M + (size_t)BB * NPART * 64);

    dim3 g1(BB, NPART);
    k1_gram<<<g1, 192, 0, stream>>>(x, S, M);
    k2_eig<<<BB, 64, 0, stream>>>(S, M, cw, vec);
    k3_mlp<<<BB, 256, 0, stream>>>(vec, pw, pb, hw, hb, out);
}

// Round 6
// 1209.184 us; speedup vs baseline: 1.4755x; 1.4755x over previous
//
#include <hip/hip_runtime.h>
#include <math.h>

// Problem constants
#define CC 62
#define TT 2000
#define BB 256
#define VECN 1953          // C*(C+1)/2
#define HID 64
#define NCLS 3
#define NPART 4            // t-parts for Grammian partials
#define TCHUNK 500         // TT / NPART
#define TTILE 100          // t-tile
#define NTILES 5           // TCHUNK / TTILE
#define LDXF 68            // sXf row stride (floats)
#define NG 31              // disjoint pairs per round

// ---------------------------------------------------------------------------
// K1: raw-x partial Grammian S = sum_t x x^T (packed triu) and partial sums
//     m = sum_t x over a 500-sample t-chunk. fp32 staging + fp32 products,
//     fp64 accumulators, stored as fp32 partials (cov err ~3e-8, harmless).
//     Conv is algebraically removed: cov(Wx+b) = W cov(x) W^T (done in k2).
// grid = (B, NPART), block = 192.
// ---------------------------------------------------------------------------
__global__ __launch_bounds__(192) void k1_gram(
    const float* __restrict__ x, float* __restrict__ S,
    float* __restrict__ M)
{
    const int b = blockIdx.x, part = blockIdx.y, tid = threadIdx.x;

    __shared__ float sXf[TTILE * LDXF];   // [t][c], 27.2KB

    // Grammian mapping: thread u<136 -> group-pair (gi<=gj) of 16 groups of 4
    int gi = 0, gj = 0;
    if (tid < 136) {
        int g = 0, rem = tid;
        while (rem >= 16 - g) { rem -= (16 - g); ++g; }
        gi = g; gj = g + rem;
    }
    const bool gram = (tid < 136);
    const int c0 = 4 * gi, c1 = 4 * gj;

    double acc64[4][4];
#pragma unroll
    for (int a = 0; a < 4; ++a)
#pragma unroll
        for (int c = 0; c < 4; ++c) acc64[a][c] = 0.0;
    double macc = 0.0;

    // zero-pad channels 62..67 once (loaders never touch them)
    for (int t = tid; t < TTILE; t += 192) {
#pragma unroll
        for (int c = CC; c < LDXF; ++c) sXf[t * LDXF + c] = 0.0f;
    }

    const float* xb = x + (size_t)b * CC * TT;
    const int tbase = part * TCHUNK;

    for (int tile = 0; tile < NTILES; ++tile) {
        const int t0 = tbase + tile * TTILE;
        __syncthreads();   // previous tile fully consumed (covers pad init too)
        // coalesced float4 loads along t; transpose into [t][c] via b32 writes
        for (int e = tid; e < CC * (TTILE / 4); e += 192) {
            int row = e / (TTILE / 4), seg = e - row * (TTILE / 4);
            float4 v = *reinterpret_cast<const float4*>(
                xb + (size_t)row * TT + t0 + seg * 4);
            int tt = seg * 4;
            sXf[(tt + 0) * LDXF + row] = v.x;
            sXf[(tt + 1) * LDXF + row] = v.y;
            sXf[(tt + 2) * LDXF + row] = v.z;
            sXf[(tt + 3) * LDXF + row] = v.w;
        }
        __syncthreads();
        // per-channel sums (fp32 within tile, fp64 upgrade)
        if (tid < CC) {
            float ms = 0.0f;
            for (int t = 0; t < TTILE; ++t) ms += sXf[t * LDXF + tid];
            macc += (double)ms;
        }
        if (gram) {
            float a32[4][4];
#pragma unroll
            for (int a = 0; a < 4; ++a)
#pragma unroll
                for (int c = 0; c < 4; ++c) a32[a][c] = 0.0f;
            for (int t = 0; t < TTILE; ++t) {
                const float* rowt = &sXf[t * LDXF];
                float4 A = *reinterpret_cast<const float4*>(&rowt[c0]);
                float4 Bv = *reinterpret_cast<const float4*>(&rowt[c1]);
                a32[0][0] += A.x * Bv.x; a32[0][1] += A.x * Bv.y;
                a32[0][2] += A.x * Bv.z; a32[0][3] += A.x * Bv.w;
                a32[1][0] += A.y * Bv.x; a32[1][1] += A.y * Bv.y;
                a32[1][2] += A.y * Bv.z; a32[1][3] += A.y * Bv.w;
                a32[2][0] += A.z * Bv.x; a32[2][1] += A.z * Bv.y;
                a32[2][2] += A.z * Bv.z; a32[2][3] += A.z * Bv.w;
                a32[3][0] += A.w * Bv.x; a32[3][1] += A.w * Bv.y;
                a32[3][2] += A.w * Bv.z; a32[3][3] += A.w * Bv.w;
            }
#pragma unroll
            for (int a = 0; a < 4; ++a)
#pragma unroll
                for (int c = 0; c < 4; ++c) acc64[a][c] += (double)a32[a][c];
        }
    }

    if (tid < CC) M[((size_t)b * NPART + part) * 64 + tid] = (float)macc;

    if (gram) {
        float* Sb = S + ((size_t)b * NPART + part) * VECN;
#pragma unroll
        for (int a = 0; a < 4; ++a) {
            int i = c0 + a;
#pragma unroll
            for (int c = 0; c < 4; ++c) {
                int j = c1 + c;
                if (j < CC && i <= j) {
                    int pi = i * CC - (i * (i - 1)) / 2 + (j - i);
                    Sb[pi] = (float)acc64[a][c];
                }
            }
        }
    }
}

// ---------------------------------------------------------------------------
// K2: assemble A = W cov_x W^T + eps I, one-sided Jacobi (2 waves/matrix,
//     4 lanes/pair, columns in registers, DPP-only reductions, no spills),
//     then log_cov = G diag(log lam / lam^2) G^T -> fp32 triu vec.
// grid = B, block = 128. LDS ~64KB.
// ---------------------------------------------------------------------------
// G column-major, 64 doubles/col; 2-row chunk c of col p stored at c ^ (p&7)
// (swizzles the bank-quad bits; 16B-aligned double2 access preserved).
__device__ __forceinline__ double2* gchunk(double* sG, int p, int c)
{
    return reinterpret_cast<double2*>(sG + p * 64 + ((c ^ (p & 7)) << 1));
}
__device__ __forceinline__ double* gelem(double* sG, int p, int r)
{
    return sG + p * 64 + ((((r >> 1) ^ (p & 7)) << 1) | (r & 1));
}

__global__ __launch_bounds__(128) void k2_eig(
    const float* __restrict__ S, const float* __restrict__ M,
    const float* __restrict__ cw, float* __restrict__ vecout)
{
    const int b = blockIdx.x, tid = threadIdx.x;

    __shared__ double sG[CC * 64];     // 31744 B, swizzled columns
    __shared__ double sOv[3844];       // 30752 B overlay: sC (1953) / sGr (3844)
    __shared__ double sNorm[64];
    __shared__ double sD[64];
    __shared__ double sMean[64];
    __shared__ int    sFlag[2];

    double* sC  = sOv;                 // packed cov_x during assembly
    double* sGr = sOv;                 // row-major G copy during reconstruct

    if (tid < CC) {
        double mm = 0.0;
        for (int p = 0; p < NPART; ++p)
            mm += (double)M[((size_t)b * NPART + p) * 64 + tid];
        sMean[tid] = mm / (double)TT;
    }
    __syncthreads();

    // packed cov_x = (S - T m m^T)/(T-1)   (incremental triangular decode)
    {
        int i = 0, rem = tid;
        while (rem >= CC - i) { rem -= (CC - i); ++i; }
        for (int pi = tid; pi < VECN; pi += 128) {
            int j = i + rem;
            double s = 0.0;
            for (int p = 0; p < NPART; ++p)
                s += (double)S[((size_t)b * NPART + p) * VECN + pi];
            sC[pi] = (s - (double)TT * sMean[i] * sMean[j]) / 1999.0;
            rem += 128;
            while (i < CC && rem >= CC - i) { rem -= (CC - i); ++i; }
        }
    }
    __syncthreads();

    // A = W C W^T + eps I. Team of 2 lanes per output column j (halves of k).
    const int aj = tid >> 1, ah = tid & 1;   // column j, half h
    const int kb = 31 * ah;
    if (tid < 124) {
        double u[31];                        // u[kk] = (C w_j)[kb+kk]
#pragma unroll
        for (int k = 0; k < 31; ++k) u[k] = 0.0;
        const float* wj = cw + aj * CC;
        for (int l = 0; l < CC; ++l) {
            double cl = (double)wj[l];
            int kp = kb;
            int idx = (kp < l) ? (kp * CC - kp * (kp - 1) / 2 + (l - kp))
                               : (l * CC - l * (l - 1) / 2 + (kp - l));
#pragma unroll
            for (int k = 0; k < 31; ++k) {
                u[k] += sC[idx] * cl;
                int kcur = kb + k;
                idx += (kcur < l) ? (61 - kcur) : 1;
            }
        }
        for (int i = 0; i < CC; ++i) {
            const float* wi = cw + i * CC + kb;
            double a = 0.0;
#pragma unroll
            for (int k = 0; k < 31; ++k) a += (double)wi[k] * u[k];
            a += __shfl_xor(a, 1, 64);
            if (ah == 0) {
                if (i == aj) a += 1e-3;
                *gelem(sG, aj, i) = a;
            }
        }
        // zero pad rows 62,63 of this column
        if (ah == 1) { *gelem(sG, aj, 62) = 0.0; *gelem(sG, aj, 63) = 0.0; }
    }
    __syncthreads();

    // initial column norms
    if (tid < CC) {
        double n = 0.0;
        for (int r = 0; r < CC; ++r) { double v = *gelem(sG, tid, r); n += v * v; }
        sNorm[tid] = n;
    }
    __syncthreads();

    // one-sided Jacobi: team g = 4 lanes; lane l2 owns chunks 4k+l2 (k=0..7).
    const int g = tid >> 2, l2 = tid & 3;
    const bool act = (g < NG);

    for (int sweep = 0; sweep < 18; ++sweep) {
        int rotAny = 0;
        // incremental round-robin schedule state (r=0 values)
        int pp, qq;
        if (g == 0) { pp = 0; qq = 61; }
        else        { pp = g; qq = 61 - g; }
        for (int r = 0; r < 61; ++r) {
            int p = pp < qq ? pp : qq;
            int q = pp < qq ? qq : pp;
            if (!act) { p = 0; q = 1; }   // idle lanes: harmless reads
            double* gp = sG + p * 64;
            double* gq = sG + q * 64;
            const int sp = p & 7, sq = q & 7;
            double2 cp[8], cq[8];
#pragma unroll
            for (int k = 0; k < 8; ++k)
                cp[k] = *reinterpret_cast<double2*>(gp + ((((k << 2) | l2) ^ sp) << 1));
#pragma unroll
            for (int k = 0; k < 8; ++k)
                cq[k] = *reinterpret_cast<double2*>(gq + ((((k << 2) | l2) ^ sq) << 1));
            double d = 0.0;
#pragma unroll
            for (int k = 0; k < 8; ++k)
                d += cp[k].x * cq[k].x + cp[k].y * cq[k].y;
            d += __shfl_xor(d, 1, 64);
            d += __shfl_xor(d, 2, 64);
            double np = sNorm[p], nq = sNorm[q];
            if (act && d * d > np * nq * 1e-12) {
                rotAny = 1;
                float thf = (float)(nq - np) / (2.0f * (float)d);
                float af = fabsf(thf);
                float tf = 1.0f / (af + sqrtf(af * af + 1.0f));
                if (thf < 0.0f) tf = -tf;
                float cf = rsqrtf(tf * tf + 1.0f);
                double c = (double)cf, sn = (double)(tf * cf);
#pragma unroll
                for (int k = 0; k < 8; ++k) {
                    double2 a = cp[k], bv = cq[k];
                    *reinterpret_cast<double2*>(gp + ((((k << 2) | l2) ^ sp) << 1)) =
                        make_double2(c * a.x - sn * bv.x, c * a.y - sn * bv.y);
                    *reinterpret_cast<double2*>(gq + ((((k << 2) | l2) ^ sq) << 1)) =
                        make_double2(sn * a.x + c * bv.x, sn * a.y + c * bv.y);
                }
                double td = (double)tf * d;
                if (l2 == 0) sNorm[p] = np - td;
                if (l2 == 1) sNorm[q] = nq + td;
            }
            // advance tournament state
            if (g > 0) pp = (pp == 61) ? 1 : pp + 1;
            qq = (qq == 61) ? 1 : qq + 1;
            __syncthreads();
        }
        unsigned long long bal = __ballot(rotAny);
        if ((tid & 63) == 0) sFlag[tid >> 6] = (bal != 0ull) ? 1 : 0;
        __syncthreads();
        if (!(sFlag[0] | sFlag[1])) break;
    }

    // lam_k^2 = ||g_k||^2 ; sD_k = log(max(lam,1e-6))/lam^2
    if (tid < CC) {
        double n = 0.0;
        for (int r = 0; r < CC; ++r) { double v = *gelem(sG, tid, r); n += v * v; }
        double lamv = sqrt(n);
        sD[tid] = log(fmax(lamv, 1e-6)) / n;
    }
    __syncthreads();

    // transpose G into row-major sGr[i][k] = G[k][i]  (overlay; sC is dead)
    for (int e = tid; e < CC * CC; e += 128) {
        int i = e / CC, k = e - i * CC;
        sGr[i * CC + k] = *gelem(sG, k, i);
    }
    __syncthreads();

    // log_cov[i][j] = sum_k sD[k] G[k][i] G[k][j]
    float* vb = vecout + (size_t)b * VECN;
    {
        int i = 0, rem = tid;
        while (rem >= CC - i) { rem -= (CC - i); ++i; }
        for (int pi = tid; pi < VECN; pi += 128) {
            int j = i + rem;
            const double* ri = sGr + i * CC;
            const double* rj = sGr + j * CC;
            double a = 0.0;
#pragma unroll
            for (int k = 0; k < CC; k += 2) {
                double2 xv = *reinterpret_cast<const double2*>(ri + k);
                double2 yv = *reinterpret_cast<const double2*>(rj + k);
                double2 dv = *reinterpret_cast<const double2*>(&sD[k]);
                a += dv.x * xv.x * yv.x + dv.y * xv.y * yv.y;
            }
            vb[pi] = (float)a;
            rem += 128;
            while (i < CC && rem >= CC - i) { rem -= (CC - i); ++i; }
        }
    }
}

// ---------------------------------------------------------------------------
// K3: feat = relu(vec @ proj_w^T + proj_b); logits = feat @ head_w^T + head_b
// grid = B, block = 256 (4-way K-split per hidden unit)
// ---------------------------------------------------------------------------
__global__ __launch_bounds__(256) void k3_mlp(
    const float* __restrict__ vecin, const float* __restrict__ pw,
    const float* __restrict__ pb, const float* __restrict__ hw,
    const float* __restrict__ hb, float* __restrict__ out)
{
    const int b = blockIdx.x;
    const int tid = threadIdx.x;
    __shared__ float sv[VECN];
    __shared__ float sp[4][HID];
    __shared__ float sf[HID];
    for (int k = tid; k < VECN; k += 256) sv[k] = vecin[(size_t)b * VECN + k];
    __syncthreads();
    const int h = tid & 63, pp = tid >> 6;
    const int k0 = (pp * VECN) >> 2, k1 = ((pp + 1) * VECN) >> 2;
    float acc = 0.0f;
    const float* w = pw + (size_t)h * VECN;
    for (int k = k0; k < k1; ++k) acc += sv[k] * w[k];
    sp[pp][h] = acc;
    __syncthreads();
    if (tid < HID) {
        float a = sp[0][tid] + sp[1][tid] + sp[2][tid] + sp[3][tid] + pb[tid];
        sf[tid] = fmaxf(a, 0.0f);
    }
    __syncthreads();
    if (tid < NCLS) {
        float o = hb[tid];
        for (int hh = 0; hh < HID; ++hh) o += sf[hh] * hw[tid * HID + hh];
        out[b * NCLS + tid] = o;
    }
}

// ---------------------------------------------------------------------------
extern "C" void kernel_launch(void* const* d_in, const int* in_sizes, int n_in,
                              void* d_out, int out_size, void* d_ws, size_t ws_size,
                              hipStream_t stream)
{
    const float* x  = (const float*)d_in[0];
    const float* cw = (const float*)d_in[1];
    // d_in[2] = conv bias: cancels in covariance, unused
    const float* pw = (const float*)d_in[3];
    const float* pb = (const float*)d_in[4];
    const float* hw = (const float*)d_in[5];
    const float* hb = (const float*)d_in[6];
    float* out = (float*)d_out;

    // workspace (all fp32 now): S [B*NPART][VECN] (8MB), M [B*NPART][64]
    // (0.25MB), vec [B][VECN] (2MB)
    float* S = (float*)d_ws;
    float* M = S + (size_t)BB * NPART * VECN;
    float* vec = M + (size_t)BB * NPART * 64;

    dim3 g1(BB, NPART);
    k1_gram<<<g1, 192, 0, stream>>>(x, S, M);
    k2_eig<<<BB, 128, 0, stream>>>(S, M, cw, vec);
    k3_mlp<<<BB, 256, 0, stream>>>(vec, pw, pb, hw, hb, out);
}